// Round 7
// baseline (650.793 us; speedup 1.0000x reference)
//
#include <hip/hip_runtime.h>
#include <hip/hip_bf16.h>
#include <math.h>

#define N 1026
#define T 8
#define H 64
#define F_IN 5
#define E 1026
#define NNZ 200000
#define TM 7
#define NG 9
#define KP 1056        // padded rows/cols for conv GEMMs (66 * 16)
#define NWB 132        // nibble words per row (1056/8)
#define RT 120         // build: rows per LDS tile
#define NT 9           // ceil(1056/120)
#define NH (N*H)
#define WT 193         // transposed Whh LDS stride (conflict-free)

#define OFF_PRICE   0
#define OFF_WIH     41040
#define OFF_WHH     42000
#define OFF_BIH     54288
#define OFF_BHH     54480
#define OFF_WIN     54672
#define OFF_WOUT    58768
#define OFF_AE      66960
#define OFF_AB      67986
#define OFF_TH1     69012
#define OFF_B1      73108
#define OFF_TH2     73172
#define OFF_B2      77268
#define OFF_W1      77332
#define OFF_W2      77780
#define OFF_APAR    78228
#define OFF_WL      78235
#define OFF_BL      78363
#define TOT_CVT     78364

typedef unsigned int u32;
typedef unsigned short u16;
typedef short bf16x8 __attribute__((ext_vector_type(8)));
typedef float f32x4 __attribute__((ext_vector_type(4)));

__device__ __forceinline__ float leakyf(float x){ return x >= 0.f ? x : 0.2f*x; }
__device__ __forceinline__ float bfbits2f(u16 u){
  union { u32 i; float f; } c; c.i = ((u32)u) << 16; return c.f;
}
__device__ __forceinline__ u16 f2bf(float f){      // round-to-nearest-even
  u32 x = __builtin_bit_cast(u32, f);
  u32 r = x + 0x7FFFu + ((x >> 16) & 1u);
  return (u16)(r >> 16);
}
// wave-uniform dtype detect: 1 if probe tensor is fp32, 0 if bf16
__device__ __forceinline__ int detect_f32(const u16* __restrict__ w){
  int lane = threadIdx.x & 63;
  int big = 0;
  for (int k = lane; k < 960; k += 64){
    float a = fabsf(bfbits2f(w[k]));
    if (!(a < 1e3f)) big = 1;
  }
  return (__ballot(big != 0) != 0ull) ? 1 : 0;
}

struct CvtPtrs { const void* p[18]; };

__global__ __launch_bounds__(256) void k_cvt(CvtPtrs ps, float* __restrict__ dst){
  const int offs[19] = {OFF_PRICE, OFF_WIH, OFF_WHH, OFF_BIH, OFF_BHH, OFF_WIN,
                        OFF_WOUT, OFF_AE, OFF_AB, OFF_TH1, OFF_B1, OFF_TH2,
                        OFF_B2, OFF_W1, OFF_W2, OFF_APAR, OFF_WL, OFF_BL, TOT_CVT};
  int isf32 = detect_f32((const u16*)ps.p[1]);
  int i = blockIdx.x*256 + threadIdx.x;
  if (i < TOT_CVT){
    int t = 0;
    #pragma unroll
    for (int k = 1; k < 18; k++) if (i >= offs[k]) t = k;
    int j = i - offs[t];
    float v;
    if (isf32) v = ((const float*)ps.p[t])[j];
    else       v = bfbits2f(((const u16*)ps.p[t])[j]);
    dst[i] = v;
  }
}

// LDS-binned incidence build. grid (NT, NG, 2): z=0 -> AHm (rows=node),
// z=1 -> AHmT (rows=edge). Bins nibble counts in LDS, then:
//   - row sums -> Dinv (z=0) / Binv (z=1)
//   - expands tile to bf16 A-matrix with plain coalesced stores (no HBM atomics)
__global__ __launch_bounds__(256) void k_build(const int* __restrict__ hypT,
                                               const int* __restrict__ hyp,
                                               u16* __restrict__ AHm,
                                               u16* __restrict__ AHmT,
                                               float* __restrict__ Dinv,
                                               float* __restrict__ Binv){
  __shared__ u32 bins[RT*NWB];          // 63,360 B
  int tid = threadIdx.x;
  int g = blockIdx.y, side = blockIdx.z;
  int r0 = blockIdx.x * RT;
  for (int k = tid; k < RT*NWB; k += 256) bins[k] = 0;
  __syncthreads();
  const int* np_; const int* ep_;
  if (g < 8){ np_ = hypT + (size_t)g*2*NNZ; ep_ = np_ + NNZ; }
  else      { np_ = hyp;                    ep_ = hyp + NNZ; }
  for (int i = tid; i < NNZ; i += 256){
    int a = np_[i], b = ep_[i];
    int row = side ? b : a;
    int col = side ? a : b;
    int rr = row - r0;
    if ((unsigned)rr < (unsigned)RT)
      atomicAdd(&bins[rr*NWB + (col>>3)], 1u << ((col&7)*4));
  }
  __syncthreads();
  int RW = KP - r0; if (RW > RT) RW = RT;     // rows to emit (last tile: 96)
  // degrees -> Dinv/Binv
  if (tid < RW){
    int gr = r0 + tid;
    if (gr < N){
      u32 s = 0;
      for (int w = 0; w < NWB; w++){
        u32 v = bins[tid*NWB + w];
        u32 a = (v & 0x0F0F0F0Fu) + ((v >> 4) & 0x0F0F0F0Fu);
        s += (a * 0x01010101u) >> 24;
      }
      float inv = s ? 1.f/(float)s : 0.f;
      (side ? Binv : Dinv)[g*N + gr] = inv;
    }
  }
  // expand nibbles -> bf16 matrix
  u16* dst = (side ? AHmT : AHm) + (size_t)g*KP*KP;
  int total = RW * NWB;
  for (int idx = tid; idx < total; idx += 256){
    int rr = idx / NWB, w = idx - rr*NWB;
    u32 v = bins[rr*NWB + w];
    bf16x8 o;
    #pragma unroll
    for (int j = 0; j < 8; j++)
      o[j] = (short)f2bf((float)((v >> (4*j)) & 0xFu));   // exact small ints
    *(bf16x8*)(dst + (size_t)(r0 + rr)*KP + w*8) = o;
  }
}

// GRU: 4 tickers per 256-thread block; WhhT transposed (stride 193, conflict-free)
__global__ __launch_bounds__(256) void k_gru(const float* __restrict__ price,
                                             const float* __restrict__ Wih,
                                             const float* __restrict__ Whh,
                                             const float* __restrict__ bih,
                                             const float* __restrict__ bhh,
                                             float* __restrict__ ctx,
                                             float* __restrict__ last){
  __shared__ float sWhhT[64*WT];
  __shared__ float sWih[192*F_IN];
  __shared__ float sbih[192], sbhh[192];
  __shared__ float sh[4][64];
  __shared__ float sx[4][T*F_IN];
  int tid = threadIdx.x, w = tid>>6, lane = tid&63;
  int n = blockIdx.x*4 + w;
  for (int idx = tid; idx < 192*64; idx += 256){
    int j = idx >> 6, d = idx & 63;
    sWhhT[d*WT + j] = Whh[idx];
  }
  for (int k = tid; k < 192*F_IN; k += 256) sWih[k] = Wih[k];
  for (int k = tid; k < 192;      k += 256){ sbih[k] = bih[k]; sbhh[k] = bhh[k]; }
  if (n < N){ for (int k = lane; k < T*F_IN; k += 64) sx[w][k] = price[(size_t)n*T*F_IN + k]; }
  else      { for (int k = lane; k < T*F_IN; k += 64) sx[w][k] = 0.f; }
  sh[w][lane] = 0.f;
  __syncthreads();
  for (int t = 0; t < T; t++){
    float ir = sbih[lane], iz = sbih[64+lane], inn = sbih[128+lane];
    #pragma unroll
    for (int d = 0; d < F_IN; d++){
      float x = sx[w][t*F_IN + d];
      ir  += x * sWih[lane*F_IN + d];
      iz  += x * sWih[(64+lane)*F_IN + d];
      inn += x * sWih[(128+lane)*F_IN + d];
    }
    float hr = sbhh[lane], hz = sbhh[64+lane], hn = sbhh[128+lane];
    for (int d = 0; d < 64; d++){
      float hv = sh[w][d];
      const float* wr = &sWhhT[d*WT];
      hr += hv * wr[lane];
      hz += hv * wr[64 + lane];
      hn += hv * wr[128 + lane];
    }
    float r  = 1.f/(1.f + expf(-(ir+hr)));
    float z  = 1.f/(1.f + expf(-(iz+hz)));
    float nn = tanhf(inn + r*hn);
    float hnew = (1.f - z)*nn + z*sh[w][lane];
    __syncthreads();
    sh[w][lane] = hnew;
    if (n < N) ctx[((size_t)n*T + t)*H + lane] = hnew;
    __syncthreads();
  }
  if (n < N) last[(size_t)n*H + lane] = sh[w][lane];
}

__global__ __launch_bounds__(256) void k_attn(const float* __restrict__ ctx,
                                              const float* __restrict__ last,
                                              const float* __restrict__ Win,
                                              const float* __restrict__ Wout,
                                              const float* __restrict__ ae,
                                              const float* __restrict__ ab,
                                              float* __restrict__ outp){
  __shared__ float sWin[4096];
  __shared__ float sWout[8192];
  __shared__ float sc[4][T*64];
  __shared__ float sl[4][64];
  __shared__ float sq[4][64];
  __shared__ float ss[4][T];
  __shared__ float sco[4][128];
  int tid = threadIdx.x, w = tid>>6, lane = tid&63;
  int n = blockIdx.x*4 + w;
  for (int k = tid; k < 1024; k += 256) ((float4*)sWin)[k]  = ((const float4*)Win)[k];
  for (int k = tid; k < 2048; k += 256) ((float4*)sWout)[k] = ((const float4*)Wout)[k];
  if (n < N){
    for (int k = lane; k < T*64; k += 64) sc[w][k] = ctx[(size_t)n*T*H + k];
    sl[w][lane] = last[(size_t)n*H + lane];
  } else {
    for (int k = lane; k < T*64; k += 64) sc[w][k] = 0.f;
    sl[w][lane] = 0.f;
  }
  __syncthreads();
  float q = 0.f;
  for (int d = 0; d < 64; d++) q += sl[w][d]*sWin[d*64 + lane];
  sq[w][lane] = q;
  __syncthreads();
  if (lane < T){
    float s = 0.f;
    for (int d = 0; d < 64; d++) s += sq[w][d]*sc[w][lane*64 + d];
    ss[w][lane] = s;
  }
  __syncthreads();
  float m = ss[w][0];
  for (int t = 1; t < T; t++) m = fmaxf(m, ss[w][t]);
  float wv[T]; float den = 0.f;
  for (int t = 0; t < T; t++){ wv[t] = expf(ss[w][t]-m); den += wv[t]; }
  float aen = (n < N) ? ae[n] : 0.f, abn = (n < N) ? ab[n] : 0.f;
  float mixs = 0.f;
  for (int t = 0; t < T; t++){
    float wt = wv[t]/den;
    float mx = wt * sc[w][t*64 + lane];
    float bt = expf(-abn * (float)(T-1-t));
    mixs += fmaxf(aen*mx*bt, 0.f) + mx;
  }
  sco[w][lane] = mixs; sco[w][64+lane] = q;
  __syncthreads();
  float o = 0.f;
  for (int k = 0; k < 128; k++) o += sco[w][k]*sWout[k*64 + lane];
  if (n < N) outp[(size_t)n*H + lane] = tanhf(o);
}

// xt = x @ theta computed in FP32 (accuracy-critical), written TRANSPOSED
// as bf16: xtT[g][f][k], k zero-padded to KP. (MFMA version regressed
// absmax 3.05e-5 -> 1.83e-4: bf16 INPUT rounding of a 64-term dot.)
__global__ __launch_bounds__(256) void k_xthetaT(const float* __restrict__ x,
                                                 const float* __restrict__ theta,
                                                 int x_per_graph,
                                                 u16* __restrict__ xtT){
  __shared__ float sth[4096];
  __shared__ float sxr[64][64];
  __shared__ float syt[64][65];
  int tid = threadIdx.x, w = tid>>6, lane = tid&63;
  int g = blockIdx.y;
  int r0 = blockIdx.x*64;
  const float* xg = x + (x_per_graph ? (size_t)g*N*64 : (size_t)0);
  for (int k = tid; k < 1024; k += 256) ((float4*)sth)[k] = ((const float4*)theta)[k];
  for (int rr = w; rr < 64; rr += 4){
    int r = r0 + rr;
    sxr[rr][lane] = (r < N) ? xg[(size_t)r*64 + lane] : 0.f;
  }
  __syncthreads();
  for (int rr = w*16; rr < w*16+16; rr++){
    float acc = 0.f;
    for (int d = 0; d < 64; d++) acc = fmaf(sxr[rr][d], sth[d*64 + lane], acc);
    syt[lane][rr] = acc;                 // bank (lane+rr)%32 -> conflict-free
  }
  __syncthreads();
  int col = r0 + lane;
  if (col < KP){
    for (int f = w*16; f < w*16+16; f++)
      xtT[((size_t)g*64 + f)*KP + col] = f2bf(syt[f][lane]);
  }
}

// MFMA conv GEMM, A directly bf16 (built by k_build). One wave = 16 rows x 64 cols.
// mode 0: Yt[g][f][m] bf16 = acc*scale[m] (pads->0); mode 1: Yf[g][m][f] fp32 leaky(+bias)
__global__ __launch_bounds__(64) void k_gemm(const u16* __restrict__ A,
                                             const u16* __restrict__ Xt,
                                             int x_per_graph,
                                             const float* __restrict__ scale,
                                             const float* __restrict__ bias,
                                             int mode,
                                             u16* __restrict__ Yt,
                                             float* __restrict__ Yf){
  int g = blockIdx.y, m0 = blockIdx.x*16, lane = threadIdx.x;
  int mrow = lane & 15, quad = lane >> 4;
  const u16* Ap = A + (size_t)g*KP*KP + (size_t)(m0 + mrow)*KP + quad*8;
  const u16* Bp = Xt + (x_per_graph ? (size_t)g*64*KP : (size_t)0)
                     + (size_t)mrow*KP + quad*8;
  f32x4 acc[4];
  #pragma unroll
  for (int nt = 0; nt < 4; nt++) acc[nt] = (f32x4){0.f,0.f,0.f,0.f};
  bf16x8 a0 = *(const bf16x8*)Ap;
  bf16x8 b0[4];
  #pragma unroll
  for (int nt = 0; nt < 4; nt++) b0[nt] = *(const bf16x8*)(Bp + (size_t)nt*16*KP);
  for (int c = 0; c < 33; c++){
    bf16x8 a1 = a0;
    bf16x8 b1[4] = {b0[0], b0[1], b0[2], b0[3]};
    if (c < 32){
      a1 = *(const bf16x8*)(Ap + (c+1)*32);
      #pragma unroll
      for (int nt = 0; nt < 4; nt++)
        b1[nt] = *(const bf16x8*)(Bp + (size_t)nt*16*KP + (c+1)*32);
    }
    #pragma unroll
    for (int nt = 0; nt < 4; nt++)
      acc[nt] = __builtin_amdgcn_mfma_f32_16x16x32_bf16(a0, b0[nt], acc[nt], 0, 0, 0);
    a0 = a1;
    #pragma unroll
    for (int nt = 0; nt < 4; nt++) b0[nt] = b1[nt];
  }
  int mbase = m0 + quad*4;
  float sc_[4];
  #pragma unroll
  for (int r = 0; r < 4; r++){
    int m = mbase + r;
    sc_[r] = (m < N) ? scale[g*N + m] : 0.f;
  }
  if (mode == 0){
    #pragma unroll
    for (int nt = 0; nt < 4; nt++){
      ushort4 o;
      o.x = f2bf(acc[nt][0]*sc_[0]);
      o.y = f2bf(acc[nt][1]*sc_[1]);
      o.z = f2bf(acc[nt][2]*sc_[2]);
      o.w = f2bf(acc[nt][3]*sc_[3]);
      *(ushort4*)(Yt + ((size_t)g*64 + nt*16 + mrow)*KP + mbase) = o;
    }
  } else {
    float bs[4];
    #pragma unroll
    for (int nt = 0; nt < 4; nt++) bs[nt] = bias[nt*16 + mrow];
    #pragma unroll
    for (int r = 0; r < 4; r++){
      int m = mbase + r;
      if (m < N){
        #pragma unroll
        for (int nt = 0; nt < 4; nt++){
          float v = acc[nt][r]*sc_[r] + bs[nt];
          Yf[((size_t)g*N + m)*64 + nt*16 + mrow] = leakyf(v);
        }
      }
    }
  }
}

// fused bmean + zred: block k computes b[k] then z[k]
__global__ __launch_bounds__(256) void k_bz(const float* __restrict__ x2,
                                            const float* __restrict__ a_param,
                                            float* __restrict__ zout){
  int k = blockIdx.x, tid = threadIdx.x;
  const float* a = x2 + (size_t)k*NH;
  const float* c = x2 + (size_t)(k+1)*NH;
  __shared__ float red[256];
  __shared__ float sbk;
  float s = 0.f;
  for (int i = tid; i < NH; i += 256) s += c[i] - a[i];
  red[tid] = s; __syncthreads();
  for (int off = 128; off; off >>= 1){ if (tid < off) red[tid] += red[tid+off]; __syncthreads(); }
  if (tid == 0) sbk = red[0] / (float)NH;
  __syncthreads();
  float bk = sbk, ap = a_param[k];
  float s2 = 0.f;
  for (int i = tid; i < NH; i += 256){
    float sub = c[i] - a[i];
    float U = 1.f/(1.f + ap*(bk - sub));
    s2 += (U*sub)/U;
  }
  red[tid] = s2; __syncthreads();
  for (int off = 128; off; off >>= 1){ if (tid < off) red[tid] += red[tid+off]; __syncthreads(); }
  if (tid == 0) zout[k] = red[0];
}

// final projection with inline wattn (softmax(w2 @ leaky(w1 @ z))) and dtype detect
__global__ __launch_bounds__(256) void k_final(const float* __restrict__ x2,
                                               const float* __restrict__ zv,
                                               const float* __restrict__ w1,
                                               const float* __restrict__ w2,
                                               const float* __restrict__ Wl,
                                               const float* __restrict__ bl,
                                               const u16* __restrict__ wihRaw,
                                               void* __restrict__ outv){
  __shared__ float sy[64];
  __shared__ float swa[8];
  int tid = threadIdx.x;
  int isf32 = detect_f32(wihRaw);
  if (tid < 64){
    float y = 0.f;
    for (int kk = 0; kk < TM; kk++) y += w1[tid*TM + kk]*zv[kk];
    sy[tid] = leakyf(y);
  }
  __syncthreads();
  if (tid < TM){
    float v = 0.f;
    for (int d = 0; d < 64; d++) v += w2[tid*64 + d]*sy[d];
    swa[tid] = v;
  }
  __syncthreads();
  if (tid == 0){
    float m = swa[0];
    for (int t = 1; t < TM; t++) m = fmaxf(m, swa[t]);
    float den = 0.f;
    for (int t = 0; t < TM; t++){ swa[t] = expf(swa[t]-m); den += swa[t]; }
    for (int t = 0; t < TM; t++) swa[t] /= den;
  }
  __syncthreads();
  int n = blockIdx.x*256 + tid;
  if (n < N){
    float w0 = swa[0], w2v = swa[2];
    float acc = bl[0];
    for (int h = 0; h < 64; h++){
      float xg = x2[(size_t)8*NH + (size_t)n*64 + h];
      float s0 = x2[(size_t)1*NH + (size_t)n*64 + h] - x2[(size_t)0*NH + (size_t)n*64 + h];
      float s2 = x2[(size_t)3*NH + (size_t)n*64 + h] - x2[(size_t)2*NH + (size_t)n*64 + h];
      float xx = w0*s0 + w2v*s2;
      acc += xg*Wl[h] + xx*Wl[64 + h];
    }
    float r = leakyf(acc);
    if (isf32) ((float*)outv)[n] = r;
    else       ((__hip_bfloat16*)outv)[n] = __float2bfloat16(r);
  }
}

extern "C" void kernel_launch(void* const* d_in, const int* in_sizes, int n_in,
                              void* d_out, int out_size, void* d_ws, size_t ws_size,
                              hipStream_t stream) {
  const int* hypT = (const int*)d_in[1];
  const int* hyp  = (const int*)d_in[2];

  char* p = (char*)d_ws;
  auto alloc = [&](size_t bytes) -> char* {
    char* r = p; p += (bytes + 63) & ~(size_t)63; return r;
  };
  float* cv   = (float*)alloc((size_t)TOT_CVT*4);
  u16* AHm    = (u16*)  alloc((size_t)NG*KP*KP*2);
  u16* AHmT   = (u16*)  alloc((size_t)NG*KP*KP*2);
  float* Dinv = (float*)alloc((size_t)NG*N*4);
  float* Binv = (float*)alloc((size_t)NG*N*4);
  float* ctx  = (float*)alloc((size_t)N*T*H*4);
  float* last = (float*)alloc((size_t)N*H*4);
  float* outp = (float*)alloc((size_t)N*H*4);
  float* x1   = (float*)alloc((size_t)NG*N*H*4);
  float* x2   = (float*)alloc((size_t)NG*N*H*4);
  float* zv   = (float*)alloc(64);
  u16* xtT1   = (u16*)  alloc((size_t)64*KP*2);
  u16* xtT2   = (u16*)  alloc((size_t)NG*64*KP*2);
  u16* ebufT  = (u16*)  alloc((size_t)NG*64*KP*2);

  const float* price  = cv + OFF_PRICE;
  const float* Wih    = cv + OFF_WIH;
  const float* Whh    = cv + OFF_WHH;
  const float* bih    = cv + OFF_BIH;
  const float* bhh    = cv + OFF_BHH;
  const float* Win    = cv + OFF_WIN;
  const float* Wout   = cv + OFF_WOUT;
  const float* ae     = cv + OFF_AE;
  const float* ab     = cv + OFF_AB;
  const float* theta1 = cv + OFF_TH1;
  const float* bias1  = cv + OFF_B1;
  const float* theta2 = cv + OFF_TH2;
  const float* bias2  = cv + OFF_B2;
  const float* w1     = cv + OFF_W1;
  const float* w2     = cv + OFF_W2;
  const float* a_par  = cv + OFF_APAR;
  const float* Wl     = cv + OFF_WL;
  const float* bl     = cv + OFF_BL;

  CvtPtrs ps;
  ps.p[0]=d_in[0];  ps.p[1]=d_in[3];  ps.p[2]=d_in[4];  ps.p[3]=d_in[5];
  ps.p[4]=d_in[6];  ps.p[5]=d_in[7];  ps.p[6]=d_in[8];  ps.p[7]=d_in[9];
  ps.p[8]=d_in[10]; ps.p[9]=d_in[11]; ps.p[10]=d_in[12]; ps.p[11]=d_in[13];
  ps.p[12]=d_in[14]; ps.p[13]=d_in[15]; ps.p[14]=d_in[16]; ps.p[15]=d_in[17];
  ps.p[16]=d_in[18]; ps.p[17]=d_in[19];
  k_cvt<<<(TOT_CVT+255)/256, 256, 0, stream>>>(ps, cv);

  k_build<<<dim3(NT, NG, 2), 256, 0, stream>>>(hypT, hyp, AHm, AHmT, Dinv, Binv);
  k_gru  <<<(N+3)/4, 256, 0, stream>>>(price, Wih, Whh, bih, bhh, ctx, last);
  k_attn <<<(N+3)/4, 256, 0, stream>>>(ctx, last, Win, Wout, ae, ab, outp);

  // layer 1
  k_xthetaT<<<dim3(17, 1), 256, 0, stream>>>(outp, theta1, 0, xtT1);
  k_gemm<<<dim3(KP/16, NG), 64, 0, stream>>>(AHmT, xtT1, 0, Binv, nullptr, 0, ebufT, nullptr);
  k_gemm<<<dim3(KP/16, NG), 64, 0, stream>>>(AHm, ebufT, 1, Dinv, bias1, 1, nullptr, x1);

  // layer 2
  k_xthetaT<<<dim3(17, NG), 256, 0, stream>>>(x1, theta2, 1, xtT2);
  k_gemm<<<dim3(KP/16, NG), 64, 0, stream>>>(AHmT, xtT2, 1, Binv, nullptr, 0, ebufT, nullptr);
  k_gemm<<<dim3(KP/16, NG), 64, 0, stream>>>(AHm, ebufT, 1, Dinv, bias2, 1, nullptr, x2);

  k_bz<<<TM, 256, 0, stream>>>(x2, a_par, zv);
  k_final<<<(N+255)/256, 256, 0, stream>>>(x2, zv, w1, w2, Wl, bl,
                                           (const u16*)d_in[3], d_out);
}

// Round 8
// 479.767 us; speedup vs baseline: 1.3565x; 1.3565x over previous
//
#include <hip/hip_runtime.h>
#include <hip/hip_bf16.h>
#include <math.h>

#define N 1026
#define T 8
#define H 64
#define F_IN 5
#define E 1026
#define NNZ 200000
#define TM 7
#define NG 9
#define KP 1056        // padded rows/cols for conv GEMMs (66 * 16)
#define NWB 132        // nibble words per row (1056/8)
#define RT 96          // build: rows per LDS tile (50.7 KB -> 3 blocks/CU)
#define NT 11          // 11*96 = 1056 exactly
#define NH (N*H)
#define WT 193         // transposed Whh LDS stride (conflict-free)

#define OFF_PRICE   0
#define OFF_WIH     41040
#define OFF_WHH     42000
#define OFF_BIH     54288
#define OFF_BHH     54480
#define OFF_WIN     54672
#define OFF_WOUT    58768
#define OFF_AE      66960
#define OFF_AB      67986
#define OFF_TH1     69012
#define OFF_B1      73108
#define OFF_TH2     73172
#define OFF_B2      77268
#define OFF_W1      77332
#define OFF_W2      77780
#define OFF_APAR    78228
#define OFF_WL      78235
#define OFF_BL      78363
#define TOT_CVT     78364

typedef unsigned int u32;
typedef unsigned short u16;
typedef short bf16x8 __attribute__((ext_vector_type(8)));
typedef float f32x4 __attribute__((ext_vector_type(4)));

__device__ __forceinline__ float leakyf(float x){ return x >= 0.f ? x : 0.2f*x; }
__device__ __forceinline__ float bfbits2f(u16 u){
  union { u32 i; float f; } c; c.i = ((u32)u) << 16; return c.f;
}
__device__ __forceinline__ u16 f2bf(float f){      // round-to-nearest-even
  u32 x = __builtin_bit_cast(u32, f);
  u32 r = x + 0x7FFFu + ((x >> 16) & 1u);
  return (u16)(r >> 16);
}
// wave-uniform dtype detect: 1 if probe tensor is fp32, 0 if bf16
__device__ __forceinline__ int detect_f32(const u16* __restrict__ w){
  int lane = threadIdx.x & 63;
  int big = 0;
  for (int k = lane; k < 960; k += 64){
    float a = fabsf(bfbits2f(w[k]));
    if (!(a < 1e3f)) big = 1;
  }
  return (__ballot(big != 0) != 0ull) ? 1 : 0;
}

struct CvtPtrs { const void* p[18]; };

__global__ __launch_bounds__(256) void k_cvt(CvtPtrs ps, float* __restrict__ dst){
  const int offs[19] = {OFF_PRICE, OFF_WIH, OFF_WHH, OFF_BIH, OFF_BHH, OFF_WIN,
                        OFF_WOUT, OFF_AE, OFF_AB, OFF_TH1, OFF_B1, OFF_TH2,
                        OFF_B2, OFF_W1, OFF_W2, OFF_APAR, OFF_WL, OFF_BL, TOT_CVT};
  int isf32 = detect_f32((const u16*)ps.p[1]);
  int i = blockIdx.x*256 + threadIdx.x;
  if (i < TOT_CVT){
    int t = 0;
    #pragma unroll
    for (int k = 1; k < 18; k++) if (i >= offs[k]) t = k;
    int j = i - offs[t];
    float v;
    if (isf32) v = ((const float*)ps.p[t])[j];
    else       v = bfbits2f(((const u16*)ps.p[t])[j]);
    dst[i] = v;
  }
}

// LDS-binned incidence build. grid (NT, NG, 2): z=0 -> AHm (rows=node),
// z=1 -> AHmT (rows=edge). int4-vectorized edge reads (R7 was latency-bound:
// scalar loads, 781 serial iters, 6.6% occupancy -> 320 us).
__global__ __launch_bounds__(256) void k_build(const int* __restrict__ hypT,
                                               const int* __restrict__ hyp,
                                               u16* __restrict__ AHm,
                                               u16* __restrict__ AHmT,
                                               float* __restrict__ Dinv,
                                               float* __restrict__ Binv){
  __shared__ u32 bins[RT*NWB];          // 50,688 B -> 3 blocks/CU
  int tid = threadIdx.x;
  int g = blockIdx.y, side = blockIdx.z;
  int r0 = blockIdx.x * RT;
  for (int k = tid; k < RT*NWB; k += 256) bins[k] = 0;
  __syncthreads();
  const int4* np4; const int4* ep4;
  if (g < 8){ const int* np_ = hypT + (size_t)g*2*NNZ;
              np4 = (const int4*)np_; ep4 = (const int4*)(np_ + NNZ); }
  else      { np4 = (const int4*)hyp; ep4 = (const int4*)(hyp + NNZ); }
  #pragma unroll 2
  for (int i = tid; i < NNZ/4; i += 256){
    int4 a4 = np4[i], b4 = ep4[i];
    int ra[4], ca[4];
    if (side){
      ra[0]=b4.x; ra[1]=b4.y; ra[2]=b4.z; ra[3]=b4.w;
      ca[0]=a4.x; ca[1]=a4.y; ca[2]=a4.z; ca[3]=a4.w;
    } else {
      ra[0]=a4.x; ra[1]=a4.y; ra[2]=a4.z; ra[3]=a4.w;
      ca[0]=b4.x; ca[1]=b4.y; ca[2]=b4.z; ca[3]=b4.w;
    }
    #pragma unroll
    for (int e = 0; e < 4; e++){
      int rr = ra[e] - r0;
      if ((unsigned)rr < (unsigned)RT)
        atomicAdd(&bins[rr*NWB + (ca[e]>>3)], 1u << ((ca[e]&7)*4));
    }
  }
  __syncthreads();
  // degrees -> Dinv/Binv
  if (tid < RT){
    int gr = r0 + tid;
    if (gr < N){
      u32 s = 0;
      for (int w = 0; w < NWB; w++){
        u32 v = bins[tid*NWB + w];
        u32 a = (v & 0x0F0F0F0Fu) + ((v >> 4) & 0x0F0F0F0Fu);
        s += (a * 0x01010101u) >> 24;
      }
      float inv = s ? 1.f/(float)s : 0.f;
      (side ? Binv : Dinv)[g*N + gr] = inv;
    }
  }
  // expand nibbles -> bf16 matrix (plain coalesced stores)
  u16* dst = (side ? AHmT : AHm) + (size_t)g*KP*KP;
  for (int idx = tid; idx < RT*NWB; idx += 256){
    int rr = idx / NWB, w = idx - rr*NWB;
    u32 v = bins[rr*NWB + w];
    bf16x8 o;
    #pragma unroll
    for (int j = 0; j < 8; j++)
      o[j] = (short)f2bf((float)((v >> (4*j)) & 0xFu));   // exact small ints
    *(bf16x8*)(dst + (size_t)(r0 + rr)*KP + w*8) = o;
  }
}

// GRU: 4 tickers per 256-thread block; WhhT transposed (stride 193, conflict-free)
__global__ __launch_bounds__(256) void k_gru(const float* __restrict__ price,
                                             const float* __restrict__ Wih,
                                             const float* __restrict__ Whh,
                                             const float* __restrict__ bih,
                                             const float* __restrict__ bhh,
                                             float* __restrict__ ctx,
                                             float* __restrict__ last){
  __shared__ float sWhhT[64*WT];
  __shared__ float sWih[192*F_IN];
  __shared__ float sbih[192], sbhh[192];
  __shared__ float sh[4][64];
  __shared__ float sx[4][T*F_IN];
  int tid = threadIdx.x, w = tid>>6, lane = tid&63;
  int n = blockIdx.x*4 + w;
  for (int idx = tid; idx < 192*64; idx += 256){
    int j = idx >> 6, d = idx & 63;
    sWhhT[d*WT + j] = Whh[idx];
  }
  for (int k = tid; k < 192*F_IN; k += 256) sWih[k] = Wih[k];
  for (int k = tid; k < 192;      k += 256){ sbih[k] = bih[k]; sbhh[k] = bhh[k]; }
  if (n < N){ for (int k = lane; k < T*F_IN; k += 64) sx[w][k] = price[(size_t)n*T*F_IN + k]; }
  else      { for (int k = lane; k < T*F_IN; k += 64) sx[w][k] = 0.f; }
  sh[w][lane] = 0.f;
  __syncthreads();
  for (int t = 0; t < T; t++){
    float ir = sbih[lane], iz = sbih[64+lane], inn = sbih[128+lane];
    #pragma unroll
    for (int d = 0; d < F_IN; d++){
      float x = sx[w][t*F_IN + d];
      ir  += x * sWih[lane*F_IN + d];
      iz  += x * sWih[(64+lane)*F_IN + d];
      inn += x * sWih[(128+lane)*F_IN + d];
    }
    float hr = sbhh[lane], hz = sbhh[64+lane], hn = sbhh[128+lane];
    for (int d = 0; d < 64; d++){
      float hv = sh[w][d];
      const float* wr = &sWhhT[d*WT];
      hr += hv * wr[lane];
      hz += hv * wr[64 + lane];
      hn += hv * wr[128 + lane];
    }
    float r  = 1.f/(1.f + expf(-(ir+hr)));
    float z  = 1.f/(1.f + expf(-(iz+hz)));
    float nn = tanhf(inn + r*hn);
    float hnew = (1.f - z)*nn + z*sh[w][lane];
    __syncthreads();
    sh[w][lane] = hnew;
    if (n < N) ctx[((size_t)n*T + t)*H + lane] = hnew;
    __syncthreads();
  }
  if (n < N) last[(size_t)n*H + lane] = sh[w][lane];
}

__global__ __launch_bounds__(256) void k_attn(const float* __restrict__ ctx,
                                              const float* __restrict__ last,
                                              const float* __restrict__ Win,
                                              const float* __restrict__ Wout,
                                              const float* __restrict__ ae,
                                              const float* __restrict__ ab,
                                              float* __restrict__ outp){
  __shared__ float sWin[4096];
  __shared__ float sWout[8192];
  __shared__ float sc[4][T*64];
  __shared__ float sl[4][64];
  __shared__ float sq[4][64];
  __shared__ float ss[4][T];
  __shared__ float sco[4][128];
  int tid = threadIdx.x, w = tid>>6, lane = tid&63;
  int n = blockIdx.x*4 + w;
  for (int k = tid; k < 1024; k += 256) ((float4*)sWin)[k]  = ((const float4*)Win)[k];
  for (int k = tid; k < 2048; k += 256) ((float4*)sWout)[k] = ((const float4*)Wout)[k];
  if (n < N){
    for (int k = lane; k < T*64; k += 64) sc[w][k] = ctx[(size_t)n*T*H + k];
    sl[w][lane] = last[(size_t)n*H + lane];
  } else {
    for (int k = lane; k < T*64; k += 64) sc[w][k] = 0.f;
    sl[w][lane] = 0.f;
  }
  __syncthreads();
  float q = 0.f;
  for (int d = 0; d < 64; d++) q += sl[w][d]*sWin[d*64 + lane];
  sq[w][lane] = q;
  __syncthreads();
  if (lane < T){
    float s = 0.f;
    for (int d = 0; d < 64; d++) s += sq[w][d]*sc[w][lane*64 + d];
    ss[w][lane] = s;
  }
  __syncthreads();
  float m = ss[w][0];
  for (int t = 1; t < T; t++) m = fmaxf(m, ss[w][t]);
  float wv[T]; float den = 0.f;
  for (int t = 0; t < T; t++){ wv[t] = expf(ss[w][t]-m); den += wv[t]; }
  float aen = (n < N) ? ae[n] : 0.f, abn = (n < N) ? ab[n] : 0.f;
  float mixs = 0.f;
  for (int t = 0; t < T; t++){
    float wt = wv[t]/den;
    float mx = wt * sc[w][t*64 + lane];
    float bt = expf(-abn * (float)(T-1-t));
    mixs += fmaxf(aen*mx*bt, 0.f) + mx;
  }
  sco[w][lane] = mixs; sco[w][64+lane] = q;
  __syncthreads();
  float o = 0.f;
  for (int k = 0; k < 128; k++) o += sco[w][k]*sWout[k*64 + lane];
  if (n < N) outp[(size_t)n*H + lane] = tanhf(o);
}

// xt = x @ theta computed in FP32 (accuracy-critical), written TRANSPOSED
// as bf16: xtT[g][f][k], k zero-padded to KP. (MFMA version regressed
// absmax 3.05e-5 -> 1.83e-4: bf16 INPUT rounding of a 64-term dot.)
__global__ __launch_bounds__(256) void k_xthetaT(const float* __restrict__ x,
                                                 const float* __restrict__ theta,
                                                 int x_per_graph,
                                                 u16* __restrict__ xtT){
  __shared__ float sth[4096];
  __shared__ float sxr[64][64];
  __shared__ float syt[64][65];
  int tid = threadIdx.x, w = tid>>6, lane = tid&63;
  int g = blockIdx.y;
  int r0 = blockIdx.x*64;
  const float* xg = x + (x_per_graph ? (size_t)g*N*64 : (size_t)0);
  for (int k = tid; k < 1024; k += 256) ((float4*)sth)[k] = ((const float4*)theta)[k];
  for (int rr = w; rr < 64; rr += 4){
    int r = r0 + rr;
    sxr[rr][lane] = (r < N) ? xg[(size_t)r*64 + lane] : 0.f;
  }
  __syncthreads();
  for (int rr = w*16; rr < w*16+16; rr++){
    float acc = 0.f;
    for (int d = 0; d < 64; d++) acc = fmaf(sxr[rr][d], sth[d*64 + lane], acc);
    syt[lane][rr] = acc;                 // bank (lane+rr)%32 -> conflict-free
  }
  __syncthreads();
  int col = r0 + lane;
  if (col < KP){
    for (int f = w*16; f < w*16+16; f++)
      xtT[((size_t)g*64 + f)*KP + col] = f2bf(syt[f][lane]);
  }
}

// MFMA conv GEMM, A directly bf16 (built by k_build). One wave = 16 rows x 64 cols.
// mode 0: Yt[g][f][m] bf16 = acc*scale[m] (pads->0); mode 1: Yf[g][m][f] fp32 leaky(+bias)
__global__ __launch_bounds__(64) void k_gemm(const u16* __restrict__ A,
                                             const u16* __restrict__ Xt,
                                             int x_per_graph,
                                             const float* __restrict__ scale,
                                             const float* __restrict__ bias,
                                             int mode,
                                             u16* __restrict__ Yt,
                                             float* __restrict__ Yf){
  int g = blockIdx.y, m0 = blockIdx.x*16, lane = threadIdx.x;
  int mrow = lane & 15, quad = lane >> 4;
  const u16* Ap = A + (size_t)g*KP*KP + (size_t)(m0 + mrow)*KP + quad*8;
  const u16* Bp = Xt + (x_per_graph ? (size_t)g*64*KP : (size_t)0)
                     + (size_t)mrow*KP + quad*8;
  f32x4 acc[4];
  #pragma unroll
  for (int nt = 0; nt < 4; nt++) acc[nt] = (f32x4){0.f,0.f,0.f,0.f};
  bf16x8 a0 = *(const bf16x8*)Ap;
  bf16x8 b0[4];
  #pragma unroll
  for (int nt = 0; nt < 4; nt++) b0[nt] = *(const bf16x8*)(Bp + (size_t)nt*16*KP);
  for (int c = 0; c < 33; c++){
    bf16x8 a1 = a0;
    bf16x8 b1[4] = {b0[0], b0[1], b0[2], b0[3]};
    if (c < 32){
      a1 = *(const bf16x8*)(Ap + (c+1)*32);
      #pragma unroll
      for (int nt = 0; nt < 4; nt++)
        b1[nt] = *(const bf16x8*)(Bp + (size_t)nt*16*KP + (c+1)*32);
    }
    #pragma unroll
    for (int nt = 0; nt < 4; nt++)
      acc[nt] = __builtin_amdgcn_mfma_f32_16x16x32_bf16(a0, b0[nt], acc[nt], 0, 0, 0);
    a0 = a1;
    #pragma unroll
    for (int nt = 0; nt < 4; nt++) b0[nt] = b1[nt];
  }
  int mbase = m0 + quad*4;
  float sc_[4];
  #pragma unroll
  for (int r = 0; r < 4; r++){
    int m = mbase + r;
    sc_[r] = (m < N) ? scale[g*N + m] : 0.f;
  }
  if (mode == 0){
    #pragma unroll
    for (int nt = 0; nt < 4; nt++){
      ushort4 o;
      o.x = f2bf(acc[nt][0]*sc_[0]);
      o.y = f2bf(acc[nt][1]*sc_[1]);
      o.z = f2bf(acc[nt][2]*sc_[2]);
      o.w = f2bf(acc[nt][3]*sc_[3]);
      *(ushort4*)(Yt + ((size_t)g*64 + nt*16 + mrow)*KP + mbase) = o;
    }
  } else {
    float bs[4];
    #pragma unroll
    for (int nt = 0; nt < 4; nt++) bs[nt] = bias[nt*16 + mrow];
    #pragma unroll
    for (int r = 0; r < 4; r++){
      int m = mbase + r;
      if (m < N){
        #pragma unroll
        for (int nt = 0; nt < 4; nt++){
          float v = acc[nt][r]*sc_[r] + bs[nt];
          Yf[((size_t)g*N + m)*64 + nt*16 + mrow] = leakyf(v);
        }
      }
    }
  }
}

// fused bmean + zred: block k computes b[k] then z[k]
__global__ __launch_bounds__(256) void k_bz(const float* __restrict__ x2,
                                            const float* __restrict__ a_param,
                                            float* __restrict__ zout){
  int k = blockIdx.x, tid = threadIdx.x;
  const float* a = x2 + (size_t)k*NH;
  const float* c = x2 + (size_t)(k+1)*NH;
  __shared__ float red[256];
  __shared__ float sbk;
  float s = 0.f;
  for (int i = tid; i < NH; i += 256) s += c[i] - a[i];
  red[tid] = s; __syncthreads();
  for (int off = 128; off; off >>= 1){ if (tid < off) red[tid] += red[tid+off]; __syncthreads(); }
  if (tid == 0) sbk = red[0] / (float)NH;
  __syncthreads();
  float bk = sbk, ap = a_param[k];
  float s2 = 0.f;
  for (int i = tid; i < NH; i += 256){
    float sub = c[i] - a[i];
    float U = 1.f/(1.f + ap*(bk - sub));
    s2 += (U*sub)/U;
  }
  red[tid] = s2; __syncthreads();
  for (int off = 128; off; off >>= 1){ if (tid < off) red[tid] += red[tid+off]; __syncthreads(); }
  if (tid == 0) zout[k] = red[0];
}

// final projection with inline wattn (softmax(w2 @ leaky(w1 @ z))) and dtype detect
__global__ __launch_bounds__(256) void k_final(const float* __restrict__ x2,
                                               const float* __restrict__ zv,
                                               const float* __restrict__ w1,
                                               const float* __restrict__ w2,
                                               const float* __restrict__ Wl,
                                               const float* __restrict__ bl,
                                               const u16* __restrict__ wihRaw,
                                               void* __restrict__ outv){
  __shared__ float sy[64];
  __shared__ float swa[8];
  int tid = threadIdx.x;
  int isf32 = detect_f32(wihRaw);
  if (tid < 64){
    float y = 0.f;
    for (int kk = 0; kk < TM; kk++) y += w1[tid*TM + kk]*zv[kk];
    sy[tid] = leakyf(y);
  }
  __syncthreads();
  if (tid < TM){
    float v = 0.f;
    for (int d = 0; d < 64; d++) v += w2[tid*64 + d]*sy[d];
    swa[tid] = v;
  }
  __syncthreads();
  if (tid == 0){
    float m = swa[0];
    for (int t = 1; t < TM; t++) m = fmaxf(m, swa[t]);
    float den = 0.f;
    for (int t = 0; t < TM; t++){ swa[t] = expf(swa[t]-m); den += swa[t]; }
    for (int t = 0; t < TM; t++) swa[t] /= den;
  }
  __syncthreads();
  int n = blockIdx.x*256 + tid;
  if (n < N){
    float w0 = swa[0], w2v = swa[2];
    float acc = bl[0];
    for (int h = 0; h < 64; h++){
      float xg = x2[(size_t)8*NH + (size_t)n*64 + h];
      float s0 = x2[(size_t)1*NH + (size_t)n*64 + h] - x2[(size_t)0*NH + (size_t)n*64 + h];
      float s2 = x2[(size_t)3*NH + (size_t)n*64 + h] - x2[(size_t)2*NH + (size_t)n*64 + h];
      float xx = w0*s0 + w2v*s2;
      acc += xg*Wl[h] + xx*Wl[64 + h];
    }
    float r = leakyf(acc);
    if (isf32) ((float*)outv)[n] = r;
    else       ((__hip_bfloat16*)outv)[n] = __float2bfloat16(r);
  }
}

extern "C" void kernel_launch(void* const* d_in, const int* in_sizes, int n_in,
                              void* d_out, int out_size, void* d_ws, size_t ws_size,
                              hipStream_t stream) {
  const int* hypT = (const int*)d_in[1];
  const int* hyp  = (const int*)d_in[2];

  char* p = (char*)d_ws;
  auto alloc = [&](size_t bytes) -> char* {
    char* r = p; p += (bytes + 63) & ~(size_t)63; return r;
  };
  float* cv   = (float*)alloc((size_t)TOT_CVT*4);
  u16* AHm    = (u16*)  alloc((size_t)NG*KP*KP*2);
  u16* AHmT   = (u16*)  alloc((size_t)NG*KP*KP*2);
  float* Dinv = (float*)alloc((size_t)NG*N*4);
  float* Binv = (float*)alloc((size_t)NG*N*4);
  float* ctx  = (float*)alloc((size_t)N*T*H*4);
  float* last = (float*)alloc((size_t)N*H*4);
  float* outp = (float*)alloc((size_t)N*H*4);
  float* x1   = (float*)alloc((size_t)NG*N*H*4);
  float* x2   = (float*)alloc((size_t)NG*N*H*4);
  float* zv   = (float*)alloc(64);
  u16* xtT1   = (u16*)  alloc((size_t)64*KP*2);
  u16* xtT2   = (u16*)  alloc((size_t)NG*64*KP*2);
  u16* ebufT  = (u16*)  alloc((size_t)NG*64*KP*2);

  const float* price  = cv + OFF_PRICE;
  const float* Wih    = cv + OFF_WIH;
  const float* Whh    = cv + OFF_WHH;
  const float* bih    = cv + OFF_BIH;
  const float* bhh    = cv + OFF_BHH;
  const float* Win    = cv + OFF_WIN;
  const float* Wout   = cv + OFF_WOUT;
  const float* ae     = cv + OFF_AE;
  const float* ab     = cv + OFF_AB;
  const float* theta1 = cv + OFF_TH1;
  const float* bias1  = cv + OFF_B1;
  const float* theta2 = cv + OFF_TH2;
  const float* bias2  = cv + OFF_B2;
  const float* w1     = cv + OFF_W1;
  const float* w2     = cv + OFF_W2;
  const float* a_par  = cv + OFF_APAR;
  const float* Wl     = cv + OFF_WL;
  const float* bl     = cv + OFF_BL;

  CvtPtrs ps;
  ps.p[0]=d_in[0];  ps.p[1]=d_in[3];  ps.p[2]=d_in[4];  ps.p[3]=d_in[5];
  ps.p[4]=d_in[6];  ps.p[5]=d_in[7];  ps.p[6]=d_in[8];  ps.p[7]=d_in[9];
  ps.p[8]=d_in[10]; ps.p[9]=d_in[11]; ps.p[10]=d_in[12]; ps.p[11]=d_in[13];
  ps.p[12]=d_in[14]; ps.p[13]=d_in[15]; ps.p[14]=d_in[16]; ps.p[15]=d_in[17];
  ps.p[16]=d_in[18]; ps.p[17]=d_in[19];
  k_cvt<<<(TOT_CVT+255)/256, 256, 0, stream>>>(ps, cv);

  k_build<<<dim3(NT, NG, 2), 256, 0, stream>>>(hypT, hyp, AHm, AHmT, Dinv, Binv);
  k_gru  <<<(N+3)/4, 256, 0, stream>>>(price, Wih, Whh, bih, bhh, ctx, last);
  k_attn <<<(N+3)/4, 256, 0, stream>>>(ctx, last, Win, Wout, ae, ab, outp);

  // layer 1
  k_xthetaT<<<dim3(17, 1), 256, 0, stream>>>(outp, theta1, 0, xtT1);
  k_gemm<<<dim3(KP/16, NG), 64, 0, stream>>>(AHmT, xtT1, 0, Binv, nullptr, 0, ebufT, nullptr);
  k_gemm<<<dim3(KP/16, NG), 64, 0, stream>>>(AHm, ebufT, 1, Dinv, bias1, 1, nullptr, x1);

  // layer 2
  k_xthetaT<<<dim3(17, NG), 256, 0, stream>>>(x1, theta2, 1, xtT2);
  k_gemm<<<dim3(KP/16, NG), 64, 0, stream>>>(AHmT, xtT2, 1, Binv, nullptr, 0, ebufT, nullptr);
  k_gemm<<<dim3(KP/16, NG), 64, 0, stream>>>(AHm, ebufT, 1, Dinv, bias2, 1, nullptr, x2);

  k_bz<<<TM, 256, 0, stream>>>(x2, a_par, zv);
  k_final<<<(N+255)/256, 256, 0, stream>>>(x2, zv, w1, w2, Wl, bl,
                                           (const u16*)d_in[3], d_out);
}

// Round 9
// 403.383 us; speedup vs baseline: 1.6133x; 1.1894x over previous
//
#include <hip/hip_runtime.h>
#include <hip/hip_bf16.h>
#include <math.h>

#define N 1026
#define T 8
#define H 64
#define F_IN 5
#define E 1026
#define NNZ 200000
#define TM 7
#define NG 9
#define KP 1056        // padded rows/cols for conv GEMMs (66 * 16)
#define NWB 132        // nibble words per row (1056/8)
#define RT 96          // build: rows per LDS tile
#define NT 11          // 11*96 = 1056 exactly
#define NH (N*H)
#define WT 193         // transposed Whh LDS stride (conflict-free)

#define OFF_PRICE   0
#define OFF_WIH     41040
#define OFF_WHH     42000
#define OFF_BIH     54288
#define OFF_BHH     54480
#define OFF_WIN     54672
#define OFF_WOUT    58768
#define OFF_AE      66960
#define OFF_AB      67986
#define OFF_TH1     69012
#define OFF_B1      73108
#define OFF_TH2     73172
#define OFF_B2      77268
#define OFF_W1      77332
#define OFF_W2      77780
#define OFF_APAR    78228
#define OFF_WL      78235
#define OFF_BL      78363
#define TOT_CVT     78364

typedef unsigned int u32;
typedef unsigned short u16;
typedef short bf16x8 __attribute__((ext_vector_type(8)));
typedef float f32x4 __attribute__((ext_vector_type(4)));

__device__ __forceinline__ float leakyf(float x){ return x >= 0.f ? x : 0.2f*x; }
__device__ __forceinline__ float bfbits2f(u16 u){
  union { u32 i; float f; } c; c.i = ((u32)u) << 16; return c.f;
}
__device__ __forceinline__ u16 f2bf(float f){      // round-to-nearest-even
  u32 x = __builtin_bit_cast(u32, f);
  u32 r = x + 0x7FFFu + ((x >> 16) & 1u);
  return (u16)(r >> 16);
}
// wave-uniform dtype detect: 1 if probe tensor is fp32, 0 if bf16
__device__ __forceinline__ int detect_f32(const u16* __restrict__ w){
  int lane = threadIdx.x & 63;
  int big = 0;
  for (int k = lane; k < 960; k += 64){
    float a = fabsf(bfbits2f(w[k]));
    if (!(a < 1e3f)) big = 1;
  }
  return (__ballot(big != 0) != 0ull) ? 1 : 0;
}

struct CvtPtrs { const void* p[18]; };

__global__ __launch_bounds__(256) void k_cvt(CvtPtrs ps, float* __restrict__ dst){
  const int offs[19] = {OFF_PRICE, OFF_WIH, OFF_WHH, OFF_BIH, OFF_BHH, OFF_WIN,
                        OFF_WOUT, OFF_AE, OFF_AB, OFF_TH1, OFF_B1, OFF_TH2,
                        OFF_B2, OFF_W1, OFF_W2, OFF_APAR, OFF_WL, OFF_BL, TOT_CVT};
  int isf32 = detect_f32((const u16*)ps.p[1]);
  int i = blockIdx.x*256 + threadIdx.x;
  if (i < TOT_CVT){
    int t = 0;
    #pragma unroll
    for (int k = 1; k < 18; k++) if (i >= offs[k]) t = k;
    int j = i - offs[t];
    float v;
    if (isf32) v = ((const float*)ps.p[t])[j];
    else       v = bfbits2f(((const u16*)ps.p[t])[j]);
    dst[i] = v;
  }
}

// LDS-binned incidence build. grid (NT, NG, 2): z=0 -> AHm (rows=node),
// z=1 -> AHmT (rows=edge). 1024 threads/block: R8's 256-thread version ran at
// 8% occupancy (<=4 waves/CU, 198 blocks on 256 CUs) -> latency-bound 130 us.
// 16 waves/block + unroll-4 int4 scan hides the L2/HBM latency.
__global__ __launch_bounds__(1024) void k_build(const int* __restrict__ hypT,
                                                const int* __restrict__ hyp,
                                                u16* __restrict__ AHm,
                                                u16* __restrict__ AHmT,
                                                float* __restrict__ Dinv,
                                                float* __restrict__ Binv){
  __shared__ u32 bins[RT*NWB];          // 50,688 B
  int tid = threadIdx.x;
  int g = blockIdx.y, side = blockIdx.z;
  int r0 = blockIdx.x * RT;
  for (int k = tid; k < RT*NWB; k += 1024) bins[k] = 0;
  __syncthreads();
  const int4* np4; const int4* ep4;
  if (g < 8){ const int* np_ = hypT + (size_t)g*2*NNZ;
              np4 = (const int4*)np_; ep4 = (const int4*)(np_ + NNZ); }
  else      { np4 = (const int4*)hyp; ep4 = (const int4*)(hyp + NNZ); }
  #pragma unroll 4
  for (int i = tid; i < NNZ/4; i += 1024){
    int4 a4 = np4[i], b4 = ep4[i];
    int ra[4], ca[4];
    if (side){
      ra[0]=b4.x; ra[1]=b4.y; ra[2]=b4.z; ra[3]=b4.w;
      ca[0]=a4.x; ca[1]=a4.y; ca[2]=a4.z; ca[3]=a4.w;
    } else {
      ra[0]=a4.x; ra[1]=a4.y; ra[2]=a4.z; ra[3]=a4.w;
      ca[0]=b4.x; ca[1]=b4.y; ca[2]=b4.z; ca[3]=b4.w;
    }
    #pragma unroll
    for (int e = 0; e < 4; e++){
      int rr = ra[e] - r0;
      if ((unsigned)rr < (unsigned)RT)
        atomicAdd(&bins[rr*NWB + (ca[e]>>3)], 1u << ((ca[e]&7)*4));
    }
  }
  __syncthreads();
  // degrees -> Dinv/Binv: 8 threads per row + shfl reduce
  {
    int r = tid >> 3, j = tid & 7;
    if (r < RT){
      u32 s = 0;
      for (int w = j; w < NWB; w += 8){
        u32 v = bins[r*NWB + w];
        u32 a = (v & 0x0F0F0F0Fu) + ((v >> 4) & 0x0F0F0F0Fu);
        s += (a * 0x01010101u) >> 24;
      }
      s += __shfl_xor(s, 1); s += __shfl_xor(s, 2); s += __shfl_xor(s, 4);
      int gr = r0 + r;
      if (j == 0 && gr < N){
        float inv = s ? 1.f/(float)s : 0.f;
        (side ? Binv : Dinv)[g*N + gr] = inv;
      }
    }
  }
  // expand nibbles -> bf16 matrix (plain coalesced stores)
  u16* dst = (side ? AHmT : AHm) + (size_t)g*KP*KP;
  for (int idx = tid; idx < RT*NWB; idx += 1024){
    int rr = idx / NWB, w = idx - rr*NWB;
    u32 v = bins[rr*NWB + w];
    bf16x8 o;
    #pragma unroll
    for (int j = 0; j < 8; j++)
      o[j] = (short)f2bf((float)((v >> (4*j)) & 0xFu));   // exact small ints
    *(bf16x8*)(dst + (size_t)(r0 + rr)*KP + w*8) = o;
  }
}

// GRU: 4 tickers per 256-thread block; WhhT transposed (stride 193, conflict-free)
__global__ __launch_bounds__(256) void k_gru(const float* __restrict__ price,
                                             const float* __restrict__ Wih,
                                             const float* __restrict__ Whh,
                                             const float* __restrict__ bih,
                                             const float* __restrict__ bhh,
                                             float* __restrict__ ctx,
                                             float* __restrict__ last){
  __shared__ float sWhhT[64*WT];
  __shared__ float sWih[192*F_IN];
  __shared__ float sbih[192], sbhh[192];
  __shared__ float sh[4][64];
  __shared__ float sx[4][T*F_IN];
  int tid = threadIdx.x, w = tid>>6, lane = tid&63;
  int n = blockIdx.x*4 + w;
  for (int idx = tid; idx < 192*64; idx += 256){
    int j = idx >> 6, d = idx & 63;
    sWhhT[d*WT + j] = Whh[idx];
  }
  for (int k = tid; k < 192*F_IN; k += 256) sWih[k] = Wih[k];
  for (int k = tid; k < 192;      k += 256){ sbih[k] = bih[k]; sbhh[k] = bhh[k]; }
  if (n < N){ for (int k = lane; k < T*F_IN; k += 64) sx[w][k] = price[(size_t)n*T*F_IN + k]; }
  else      { for (int k = lane; k < T*F_IN; k += 64) sx[w][k] = 0.f; }
  sh[w][lane] = 0.f;
  __syncthreads();
  for (int t = 0; t < T; t++){
    float ir = sbih[lane], iz = sbih[64+lane], inn = sbih[128+lane];
    #pragma unroll
    for (int d = 0; d < F_IN; d++){
      float x = sx[w][t*F_IN + d];
      ir  += x * sWih[lane*F_IN + d];
      iz  += x * sWih[(64+lane)*F_IN + d];
      inn += x * sWih[(128+lane)*F_IN + d];
    }
    float hr = sbhh[lane], hz = sbhh[64+lane], hn = sbhh[128+lane];
    for (int d = 0; d < 64; d++){
      float hv = sh[w][d];
      const float* wr = &sWhhT[d*WT];
      hr += hv * wr[lane];
      hz += hv * wr[64 + lane];
      hn += hv * wr[128 + lane];
    }
    float r  = 1.f/(1.f + expf(-(ir+hr)));
    float z  = 1.f/(1.f + expf(-(iz+hz)));
    float nn = tanhf(inn + r*hn);
    float hnew = (1.f - z)*nn + z*sh[w][lane];
    __syncthreads();
    sh[w][lane] = hnew;
    if (n < N) ctx[((size_t)n*T + t)*H + lane] = hnew;
    __syncthreads();
  }
  if (n < N) last[(size_t)n*H + lane] = sh[w][lane];
}

__global__ __launch_bounds__(256) void k_attn(const float* __restrict__ ctx,
                                              const float* __restrict__ last,
                                              const float* __restrict__ Win,
                                              const float* __restrict__ Wout,
                                              const float* __restrict__ ae,
                                              const float* __restrict__ ab,
                                              float* __restrict__ outp){
  __shared__ float sWin[4096];
  __shared__ float sWout[8192];
  __shared__ float sc[4][T*64];
  __shared__ float sl[4][64];
  __shared__ float sq[4][64];
  __shared__ float ss[4][T];
  __shared__ float sco[4][128];
  int tid = threadIdx.x, w = tid>>6, lane = tid&63;
  int n = blockIdx.x*4 + w;
  for (int k = tid; k < 1024; k += 256) ((float4*)sWin)[k]  = ((const float4*)Win)[k];
  for (int k = tid; k < 2048; k += 256) ((float4*)sWout)[k] = ((const float4*)Wout)[k];
  if (n < N){
    for (int k = lane; k < T*64; k += 64) sc[w][k] = ctx[(size_t)n*T*H + k];
    sl[w][lane] = last[(size_t)n*H + lane];
  } else {
    for (int k = lane; k < T*64; k += 64) sc[w][k] = 0.f;
    sl[w][lane] = 0.f;
  }
  __syncthreads();
  float q = 0.f;
  for (int d = 0; d < 64; d++) q += sl[w][d]*sWin[d*64 + lane];
  sq[w][lane] = q;
  __syncthreads();
  if (lane < T){
    float s = 0.f;
    for (int d = 0; d < 64; d++) s += sq[w][d]*sc[w][lane*64 + d];
    ss[w][lane] = s;
  }
  __syncthreads();
  float m = ss[w][0];
  for (int t = 1; t < T; t++) m = fmaxf(m, ss[w][t]);
  float wv[T]; float den = 0.f;
  for (int t = 0; t < T; t++){ wv[t] = expf(ss[w][t]-m); den += wv[t]; }
  float aen = (n < N) ? ae[n] : 0.f, abn = (n < N) ? ab[n] : 0.f;
  float mixs = 0.f;
  for (int t = 0; t < T; t++){
    float wt = wv[t]/den;
    float mx = wt * sc[w][t*64 + lane];
    float bt = expf(-abn * (float)(T-1-t));
    mixs += fmaxf(aen*mx*bt, 0.f) + mx;
  }
  sco[w][lane] = mixs; sco[w][64+lane] = q;
  __syncthreads();
  float o = 0.f;
  for (int k = 0; k < 128; k++) o += sco[w][k]*sWout[k*64 + lane];
  if (n < N) outp[(size_t)n*H + lane] = tanhf(o);
}

// xt = x @ theta computed in FP32 (accuracy-critical), written TRANSPOSED
// as bf16: xtT[g][f][k], k zero-padded to KP. (MFMA version regressed
// absmax 3.05e-5 -> 1.83e-4: bf16 INPUT rounding of a 64-term dot.)
__global__ __launch_bounds__(256) void k_xthetaT(const float* __restrict__ x,
                                                 const float* __restrict__ theta,
                                                 int x_per_graph,
                                                 u16* __restrict__ xtT){
  __shared__ float sth[4096];
  __shared__ float sxr[64][64];
  __shared__ float syt[64][65];
  int tid = threadIdx.x, w = tid>>6, lane = tid&63;
  int g = blockIdx.y;
  int r0 = blockIdx.x*64;
  const float* xg = x + (x_per_graph ? (size_t)g*N*64 : (size_t)0);
  for (int k = tid; k < 1024; k += 256) ((float4*)sth)[k] = ((const float4*)theta)[k];
  for (int rr = w; rr < 64; rr += 4){
    int r = r0 + rr;
    sxr[rr][lane] = (r < N) ? xg[(size_t)r*64 + lane] : 0.f;
  }
  __syncthreads();
  for (int rr = w*16; rr < w*16+16; rr++){
    float acc = 0.f;
    for (int d = 0; d < 64; d++) acc = fmaf(sxr[rr][d], sth[d*64 + lane], acc);
    syt[lane][rr] = acc;                 // bank (lane+rr)%32 -> conflict-free
  }
  __syncthreads();
  int col = r0 + lane;
  if (col < KP){
    for (int f = w*16; f < w*16+16; f++)
      xtT[((size_t)g*64 + f)*KP + col] = f2bf(syt[f][lane]);
  }
}

// MFMA conv GEMM, A directly bf16 (built by k_build). One wave = 16 rows x 64 cols.
// mode 0: Yt[g][f][m] bf16 = acc*scale[m] (pads->0); mode 1: Yf[g][m][f] fp32 leaky(+bias)
__global__ __launch_bounds__(64) void k_gemm(const u16* __restrict__ A,
                                             const u16* __restrict__ Xt,
                                             int x_per_graph,
                                             const float* __restrict__ scale,
                                             const float* __restrict__ bias,
                                             int mode,
                                             u16* __restrict__ Yt,
                                             float* __restrict__ Yf){
  int g = blockIdx.y, m0 = blockIdx.x*16, lane = threadIdx.x;
  int mrow = lane & 15, quad = lane >> 4;
  const u16* Ap = A + (size_t)g*KP*KP + (size_t)(m0 + mrow)*KP + quad*8;
  const u16* Bp = Xt + (x_per_graph ? (size_t)g*64*KP : (size_t)0)
                     + (size_t)mrow*KP + quad*8;
  f32x4 acc[4];
  #pragma unroll
  for (int nt = 0; nt < 4; nt++) acc[nt] = (f32x4){0.f,0.f,0.f,0.f};
  bf16x8 a0 = *(const bf16x8*)Ap;
  bf16x8 b0[4];
  #pragma unroll
  for (int nt = 0; nt < 4; nt++) b0[nt] = *(const bf16x8*)(Bp + (size_t)nt*16*KP);
  for (int c = 0; c < 33; c++){
    bf16x8 a1 = a0;
    bf16x8 b1[4] = {b0[0], b0[1], b0[2], b0[3]};
    if (c < 32){
      a1 = *(const bf16x8*)(Ap + (c+1)*32);
      #pragma unroll
      for (int nt = 0; nt < 4; nt++)
        b1[nt] = *(const bf16x8*)(Bp + (size_t)nt*16*KP + (c+1)*32);
    }
    #pragma unroll
    for (int nt = 0; nt < 4; nt++)
      acc[nt] = __builtin_amdgcn_mfma_f32_16x16x32_bf16(a0, b0[nt], acc[nt], 0, 0, 0);
    a0 = a1;
    #pragma unroll
    for (int nt = 0; nt < 4; nt++) b0[nt] = b1[nt];
  }
  int mbase = m0 + quad*4;
  float sc_[4];
  #pragma unroll
  for (int r = 0; r < 4; r++){
    int m = mbase + r;
    sc_[r] = (m < N) ? scale[g*N + m] : 0.f;
  }
  if (mode == 0){
    #pragma unroll
    for (int nt = 0; nt < 4; nt++){
      ushort4 o;
      o.x = f2bf(acc[nt][0]*sc_[0]);
      o.y = f2bf(acc[nt][1]*sc_[1]);
      o.z = f2bf(acc[nt][2]*sc_[2]);
      o.w = f2bf(acc[nt][3]*sc_[3]);
      *(ushort4*)(Yt + ((size_t)g*64 + nt*16 + mrow)*KP + mbase) = o;
    }
  } else {
    float bs[4];
    #pragma unroll
    for (int nt = 0; nt < 4; nt++) bs[nt] = bias[nt*16 + mrow];
    #pragma unroll
    for (int r = 0; r < 4; r++){
      int m = mbase + r;
      if (m < N){
        #pragma unroll
        for (int nt = 0; nt < 4; nt++){
          float v = acc[nt][r]*sc_[r] + bs[nt];
          Yf[((size_t)g*N + m)*64 + nt*16 + mrow] = leakyf(v);
        }
      }
    }
  }
}

// fused bmean + zred: block k computes b[k] then z[k]
__global__ __launch_bounds__(256) void k_bz(const float* __restrict__ x2,
                                            const float* __restrict__ a_param,
                                            float* __restrict__ zout){
  int k = blockIdx.x, tid = threadIdx.x;
  const float* a = x2 + (size_t)k*NH;
  const float* c = x2 + (size_t)(k+1)*NH;
  __shared__ float red[256];
  __shared__ float sbk;
  float s = 0.f;
  for (int i = tid; i < NH; i += 256) s += c[i] - a[i];
  red[tid] = s; __syncthreads();
  for (int off = 128; off; off >>= 1){ if (tid < off) red[tid] += red[tid+off]; __syncthreads(); }
  if (tid == 0) sbk = red[0] / (float)NH;
  __syncthreads();
  float bk = sbk, ap = a_param[k];
  float s2 = 0.f;
  for (int i = tid; i < NH; i += 256){
    float sub = c[i] - a[i];
    float U = 1.f/(1.f + ap*(bk - sub));
    s2 += (U*sub)/U;
  }
  red[tid] = s2; __syncthreads();
  for (int off = 128; off; off >>= 1){ if (tid < off) red[tid] += red[tid+off]; __syncthreads(); }
  if (tid == 0) zout[k] = red[0];
}

// final projection with inline wattn (softmax(w2 @ leaky(w1 @ z))) and dtype detect
__global__ __launch_bounds__(256) void k_final(const float* __restrict__ x2,
                                               const float* __restrict__ zv,
                                               const float* __restrict__ w1,
                                               const float* __restrict__ w2,
                                               const float* __restrict__ Wl,
                                               const float* __restrict__ bl,
                                               const u16* __restrict__ wihRaw,
                                               void* __restrict__ outv){
  __shared__ float sy[64];
  __shared__ float swa[8];
  int tid = threadIdx.x;
  int isf32 = detect_f32(wihRaw);
  if (tid < 64){
    float y = 0.f;
    for (int kk = 0; kk < TM; kk++) y += w1[tid*TM + kk]*zv[kk];
    sy[tid] = leakyf(y);
  }
  __syncthreads();
  if (tid < TM){
    float v = 0.f;
    for (int d = 0; d < 64; d++) v += w2[tid*64 + d]*sy[d];
    swa[tid] = v;
  }
  __syncthreads();
  if (tid == 0){
    float m = swa[0];
    for (int t = 1; t < TM; t++) m = fmaxf(m, swa[t]);
    float den = 0.f;
    for (int t = 0; t < TM; t++){ swa[t] = expf(swa[t]-m); den += swa[t]; }
    for (int t = 0; t < TM; t++) swa[t] /= den;
  }
  __syncthreads();
  int n = blockIdx.x*256 + tid;
  if (n < N){
    float w0 = swa[0], w2v = swa[2];
    float acc = bl[0];
    for (int h = 0; h < 64; h++){
      float xg = x2[(size_t)8*NH + (size_t)n*64 + h];
      float s0 = x2[(size_t)1*NH + (size_t)n*64 + h] - x2[(size_t)0*NH + (size_t)n*64 + h];
      float s2 = x2[(size_t)3*NH + (size_t)n*64 + h] - x2[(size_t)2*NH + (size_t)n*64 + h];
      float xx = w0*s0 + w2v*s2;
      acc += xg*Wl[h] + xx*Wl[64 + h];
    }
    float r = leakyf(acc);
    if (isf32) ((float*)outv)[n] = r;
    else       ((__hip_bfloat16*)outv)[n] = __float2bfloat16(r);
  }
}

extern "C" void kernel_launch(void* const* d_in, const int* in_sizes, int n_in,
                              void* d_out, int out_size, void* d_ws, size_t ws_size,
                              hipStream_t stream) {
  const int* hypT = (const int*)d_in[1];
  const int* hyp  = (const int*)d_in[2];

  char* p = (char*)d_ws;
  auto alloc = [&](size_t bytes) -> char* {
    char* r = p; p += (bytes + 63) & ~(size_t)63; return r;
  };
  float* cv   = (float*)alloc((size_t)TOT_CVT*4);
  u16* AHm    = (u16*)  alloc((size_t)NG*KP*KP*2);
  u16* AHmT   = (u16*)  alloc((size_t)NG*KP*KP*2);
  float* Dinv = (float*)alloc((size_t)NG*N*4);
  float* Binv = (float*)alloc((size_t)NG*N*4);
  float* ctx  = (float*)alloc((size_t)N*T*H*4);
  float* last = (float*)alloc((size_t)N*H*4);
  float* outp = (float*)alloc((size_t)N*H*4);
  float* x1   = (float*)alloc((size_t)NG*N*H*4);
  float* x2   = (float*)alloc((size_t)NG*N*H*4);
  float* zv   = (float*)alloc(64);
  u16* xtT1   = (u16*)  alloc((size_t)64*KP*2);
  u16* xtT2   = (u16*)  alloc((size_t)NG*64*KP*2);
  u16* ebufT  = (u16*)  alloc((size_t)NG*64*KP*2);

  const float* price  = cv + OFF_PRICE;
  const float* Wih    = cv + OFF_WIH;
  const float* Whh    = cv + OFF_WHH;
  const float* bih    = cv + OFF_BIH;
  const float* bhh    = cv + OFF_BHH;
  const float* Win    = cv + OFF_WIN;
  const float* Wout   = cv + OFF_WOUT;
  const float* ae     = cv + OFF_AE;
  const float* ab     = cv + OFF_AB;
  const float* theta1 = cv + OFF_TH1;
  const float* bias1  = cv + OFF_B1;
  const float* theta2 = cv + OFF_TH2;
  const float* bias2  = cv + OFF_B2;
  const float* w1     = cv + OFF_W1;
  const float* w2     = cv + OFF_W2;
  const float* a_par  = cv + OFF_APAR;
  const float* Wl     = cv + OFF_WL;
  const float* bl     = cv + OFF_BL;

  CvtPtrs ps;
  ps.p[0]=d_in[0];  ps.p[1]=d_in[3];  ps.p[2]=d_in[4];  ps.p[3]=d_in[5];
  ps.p[4]=d_in[6];  ps.p[5]=d_in[7];  ps.p[6]=d_in[8];  ps.p[7]=d_in[9];
  ps.p[8]=d_in[10]; ps.p[9]=d_in[11]; ps.p[10]=d_in[12]; ps.p[11]=d_in[13];
  ps.p[12]=d_in[14]; ps.p[13]=d_in[15]; ps.p[14]=d_in[16]; ps.p[15]=d_in[17];
  ps.p[16]=d_in[18]; ps.p[17]=d_in[19];
  k_cvt<<<(TOT_CVT+255)/256, 256, 0, stream>>>(ps, cv);

  k_build<<<dim3(NT, NG, 2), 1024, 0, stream>>>(hypT, hyp, AHm, AHmT, Dinv, Binv);
  k_gru  <<<(N+3)/4, 256, 0, stream>>>(price, Wih, Whh, bih, bhh, ctx, last);
  k_attn <<<(N+3)/4, 256, 0, stream>>>(ctx, last, Win, Wout, ae, ab, outp);

  // layer 1
  k_xthetaT<<<dim3(17, 1), 256, 0, stream>>>(outp, theta1, 0, xtT1);
  k_gemm<<<dim3(KP/16, NG), 64, 0, stream>>>(AHmT, xtT1, 0, Binv, nullptr, 0, ebufT, nullptr);
  k_gemm<<<dim3(KP/16, NG), 64, 0, stream>>>(AHm, ebufT, 1, Dinv, bias1, 1, nullptr, x1);

  // layer 2
  k_xthetaT<<<dim3(17, NG), 256, 0, stream>>>(x1, theta2, 1, xtT2);
  k_gemm<<<dim3(KP/16, NG), 64, 0, stream>>>(AHmT, xtT2, 1, Binv, nullptr, 0, ebufT, nullptr);
  k_gemm<<<dim3(KP/16, NG), 64, 0, stream>>>(AHm, ebufT, 1, Dinv, bias2, 1, nullptr, x2);

  k_bz<<<TM, 256, 0, stream>>>(x2, a_par, zv);
  k_final<<<(N+255)/256, 256, 0, stream>>>(x2, zv, w1, w2, Wl, bl,
                                           (const u16*)d_in[3], d_out);
}

// Round 10
// 296.277 us; speedup vs baseline: 2.1966x; 1.3615x over previous
//
#include <hip/hip_runtime.h>
#include <hip/hip_bf16.h>
#include <math.h>

#define N 1026
#define T 8
#define H 64
#define F_IN 5
#define E 1026
#define NNZ 200000
#define TM 7
#define NG 9
#define KP 1056        // padded rows/cols for conv GEMMs (66 * 16)
#define NWB 132        // nibble words per row (1056/8)
#define RT 96          // build: rows per LDS tile
#define NT 11          // 11*96 = 1056 exactly
#define NH (N*H)
#define WT 193         // transposed Whh LDS stride (conflict-free)

#define OFF_PRICE   0
#define OFF_WIH     41040
#define OFF_WHH     42000
#define OFF_BIH     54288
#define OFF_BHH     54480
#define OFF_WIN     54672
#define OFF_WOUT    58768
#define OFF_AE      66960
#define OFF_AB      67986
#define OFF_TH1     69012
#define OFF_B1      73108
#define OFF_TH2     73172
#define OFF_B2      77268
#define OFF_W1      77332
#define OFF_W2      77780
#define OFF_APAR    78228
#define OFF_WL      78235
#define OFF_BL      78363
#define TOT_CVT     78364

typedef unsigned int u32;
typedef unsigned short u16;
typedef short bf16x8 __attribute__((ext_vector_type(8)));
typedef float f32x4 __attribute__((ext_vector_type(4)));

__device__ __forceinline__ float leakyf(float x){ return x >= 0.f ? x : 0.2f*x; }
__device__ __forceinline__ float bfbits2f(u16 u){
  union { u32 i; float f; } c; c.i = ((u32)u) << 16; return c.f;
}
__device__ __forceinline__ u16 f2bf(float f){      // round-to-nearest-even
  u32 x = __builtin_bit_cast(u32, f);
  u32 r = x + 0x7FFFu + ((x >> 16) & 1u);
  return (u16)(r >> 16);
}
// wave-uniform dtype detect: 1 if probe tensor is fp32, 0 if bf16
__device__ __forceinline__ int detect_f32(const u16* __restrict__ w){
  int lane = threadIdx.x & 63;
  int big = 0;
  for (int k = lane; k < 960; k += 64){
    float a = fabsf(bfbits2f(w[k]));
    if (!(a < 1e3f)) big = 1;
  }
  return (__ballot(big != 0) != 0ull) ? 1 : 0;
}

struct CvtPtrs { const void* p[18]; };

__global__ __launch_bounds__(256) void k_cvt(CvtPtrs ps, float* __restrict__ dst){
  const int offs[19] = {OFF_PRICE, OFF_WIH, OFF_WHH, OFF_BIH, OFF_BHH, OFF_WIN,
                        OFF_WOUT, OFF_AE, OFF_AB, OFF_TH1, OFF_B1, OFF_TH2,
                        OFF_B2, OFF_W1, OFF_W2, OFF_APAR, OFF_WL, OFF_BL, TOT_CVT};
  int isf32 = detect_f32((const u16*)ps.p[1]);
  int i = blockIdx.x*256 + threadIdx.x;
  if (i < TOT_CVT){
    int t = 0;
    #pragma unroll
    for (int k = 1; k < 18; k++) if (i >= offs[k]) t = k;
    int j = i - offs[t];
    float v;
    if (isf32) v = ((const float*)ps.p[t])[j];
    else       v = bfbits2f(((const u16*)ps.p[t])[j]);
    dst[i] = v;
  }
}

// LDS-binned incidence build. grid (NT, NG, 2): z=0 -> AHm (rows=node),
// z=1 -> AHmT (rows=edge). 1024 threads/block + int4 scan (latency hiding).
__global__ __launch_bounds__(1024) void k_build(const int* __restrict__ hypT,
                                                const int* __restrict__ hyp,
                                                u16* __restrict__ AHm,
                                                u16* __restrict__ AHmT,
                                                float* __restrict__ Dinv,
                                                float* __restrict__ Binv){
  __shared__ u32 bins[RT*NWB];          // 50,688 B
  int tid = threadIdx.x;
  int g = blockIdx.y, side = blockIdx.z;
  int r0 = blockIdx.x * RT;
  for (int k = tid; k < RT*NWB; k += 1024) bins[k] = 0;
  __syncthreads();
  const int4* np4; const int4* ep4;
  if (g < 8){ const int* np_ = hypT + (size_t)g*2*NNZ;
              np4 = (const int4*)np_; ep4 = (const int4*)(np_ + NNZ); }
  else      { np4 = (const int4*)hyp; ep4 = (const int4*)(hyp + NNZ); }
  #pragma unroll 4
  for (int i = tid; i < NNZ/4; i += 1024){
    int4 a4 = np4[i], b4 = ep4[i];
    int ra[4], ca[4];
    if (side){
      ra[0]=b4.x; ra[1]=b4.y; ra[2]=b4.z; ra[3]=b4.w;
      ca[0]=a4.x; ca[1]=a4.y; ca[2]=a4.z; ca[3]=a4.w;
    } else {
      ra[0]=a4.x; ra[1]=a4.y; ra[2]=a4.z; ra[3]=a4.w;
      ca[0]=b4.x; ca[1]=b4.y; ca[2]=b4.z; ca[3]=b4.w;
    }
    #pragma unroll
    for (int e = 0; e < 4; e++){
      int rr = ra[e] - r0;
      if ((unsigned)rr < (unsigned)RT)
        atomicAdd(&bins[rr*NWB + (ca[e]>>3)], 1u << ((ca[e]&7)*4));
    }
  }
  __syncthreads();
  // degrees -> Dinv/Binv: 8 threads per row + shfl reduce
  {
    int r = tid >> 3, j = tid & 7;
    if (r < RT){
      u32 s = 0;
      for (int w = j; w < NWB; w += 8){
        u32 v = bins[r*NWB + w];
        u32 a = (v & 0x0F0F0F0Fu) + ((v >> 4) & 0x0F0F0F0Fu);
        s += (a * 0x01010101u) >> 24;
      }
      s += __shfl_xor(s, 1); s += __shfl_xor(s, 2); s += __shfl_xor(s, 4);
      int gr = r0 + r;
      if (j == 0 && gr < N){
        float inv = s ? 1.f/(float)s : 0.f;
        (side ? Binv : Dinv)[g*N + gr] = inv;
      }
    }
  }
  // expand nibbles -> bf16 matrix (plain coalesced stores)
  u16* dst = (side ? AHmT : AHm) + (size_t)g*KP*KP;
  for (int idx = tid; idx < RT*NWB; idx += 1024){
    int rr = idx / NWB, w = idx - rr*NWB;
    u32 v = bins[rr*NWB + w];
    bf16x8 o;
    #pragma unroll
    for (int j = 0; j < 8; j++)
      o[j] = (short)f2bf((float)((v >> (4*j)) & 0xFu));   // exact small ints
    *(bf16x8*)(dst + (size_t)(r0 + rr)*KP + w*8) = o;
  }
}

// GRU: 4 tickers per 256-thread block; WhhT transposed (stride 193, conflict-free)
__global__ __launch_bounds__(256) void k_gru(const float* __restrict__ price,
                                             const float* __restrict__ Wih,
                                             const float* __restrict__ Whh,
                                             const float* __restrict__ bih,
                                             const float* __restrict__ bhh,
                                             float* __restrict__ ctx,
                                             float* __restrict__ last){
  __shared__ float sWhhT[64*WT];
  __shared__ float sWih[192*F_IN];
  __shared__ float sbih[192], sbhh[192];
  __shared__ float sh[4][64];
  __shared__ float sx[4][T*F_IN];
  int tid = threadIdx.x, w = tid>>6, lane = tid&63;
  int n = blockIdx.x*4 + w;
  for (int idx = tid; idx < 192*64; idx += 256){
    int j = idx >> 6, d = idx & 63;
    sWhhT[d*WT + j] = Whh[idx];
  }
  for (int k = tid; k < 192*F_IN; k += 256) sWih[k] = Wih[k];
  for (int k = tid; k < 192;      k += 256){ sbih[k] = bih[k]; sbhh[k] = bhh[k]; }
  if (n < N){ for (int k = lane; k < T*F_IN; k += 64) sx[w][k] = price[(size_t)n*T*F_IN + k]; }
  else      { for (int k = lane; k < T*F_IN; k += 64) sx[w][k] = 0.f; }
  sh[w][lane] = 0.f;
  __syncthreads();
  for (int t = 0; t < T; t++){
    float ir = sbih[lane], iz = sbih[64+lane], inn = sbih[128+lane];
    #pragma unroll
    for (int d = 0; d < F_IN; d++){
      float x = sx[w][t*F_IN + d];
      ir  += x * sWih[lane*F_IN + d];
      iz  += x * sWih[(64+lane)*F_IN + d];
      inn += x * sWih[(128+lane)*F_IN + d];
    }
    float hr = sbhh[lane], hz = sbhh[64+lane], hn = sbhh[128+lane];
    for (int d = 0; d < 64; d++){
      float hv = sh[w][d];
      const float* wr = &sWhhT[d*WT];
      hr += hv * wr[lane];
      hz += hv * wr[64 + lane];
      hn += hv * wr[128 + lane];
    }
    float r  = 1.f/(1.f + expf(-(ir+hr)));
    float z  = 1.f/(1.f + expf(-(iz+hz)));
    float nn = tanhf(inn + r*hn);
    float hnew = (1.f - z)*nn + z*sh[w][lane];
    __syncthreads();
    sh[w][lane] = hnew;
    if (n < N) ctx[((size_t)n*T + t)*H + lane] = hnew;
    __syncthreads();
  }
  if (n < N) last[(size_t)n*H + lane] = sh[w][lane];
}

__global__ __launch_bounds__(256) void k_attn(const float* __restrict__ ctx,
                                              const float* __restrict__ last,
                                              const float* __restrict__ Win,
                                              const float* __restrict__ Wout,
                                              const float* __restrict__ ae,
                                              const float* __restrict__ ab,
                                              float* __restrict__ outp){
  __shared__ float sWin[4096];
  __shared__ float sWout[8192];
  __shared__ float sc[4][T*64];
  __shared__ float sl[4][64];
  __shared__ float sq[4][64];
  __shared__ float ss[4][T];
  __shared__ float sco[4][128];
  int tid = threadIdx.x, w = tid>>6, lane = tid&63;
  int n = blockIdx.x*4 + w;
  for (int k = tid; k < 1024; k += 256) ((float4*)sWin)[k]  = ((const float4*)Win)[k];
  for (int k = tid; k < 2048; k += 256) ((float4*)sWout)[k] = ((const float4*)Wout)[k];
  if (n < N){
    for (int k = lane; k < T*64; k += 64) sc[w][k] = ctx[(size_t)n*T*H + k];
    sl[w][lane] = last[(size_t)n*H + lane];
  } else {
    for (int k = lane; k < T*64; k += 64) sc[w][k] = 0.f;
    sl[w][lane] = 0.f;
  }
  __syncthreads();
  float q = 0.f;
  for (int d = 0; d < 64; d++) q += sl[w][d]*sWin[d*64 + lane];
  sq[w][lane] = q;
  __syncthreads();
  if (lane < T){
    float s = 0.f;
    for (int d = 0; d < 64; d++) s += sq[w][d]*sc[w][lane*64 + d];
    ss[w][lane] = s;
  }
  __syncthreads();
  float m = ss[w][0];
  for (int t = 1; t < T; t++) m = fmaxf(m, ss[w][t]);
  float wv[T]; float den = 0.f;
  for (int t = 0; t < T; t++){ wv[t] = expf(ss[w][t]-m); den += wv[t]; }
  float aen = (n < N) ? ae[n] : 0.f, abn = (n < N) ? ab[n] : 0.f;
  float mixs = 0.f;
  for (int t = 0; t < T; t++){
    float wt = wv[t]/den;
    float mx = wt * sc[w][t*64 + lane];
    float bt = expf(-abn * (float)(T-1-t));
    mixs += fmaxf(aen*mx*bt, 0.f) + mx;
  }
  sco[w][lane] = mixs; sco[w][64+lane] = q;
  __syncthreads();
  float o = 0.f;
  for (int k = 0; k < 128; k++) o += sco[w][k]*sWout[k*64 + lane];
  if (n < N) outp[(size_t)n*H + lane] = tanhf(o);
}

// xt = x @ theta computed in FP32 (accuracy-critical), written TRANSPOSED
// as bf16: xtT[g][f][k], k zero-padded to KP. (MFMA version regressed
// absmax 3.05e-5 -> 1.83e-4: bf16 INPUT rounding of a 64-term dot.)
__global__ __launch_bounds__(256) void k_xthetaT(const float* __restrict__ x,
                                                 const float* __restrict__ theta,
                                                 int x_per_graph,
                                                 u16* __restrict__ xtT){
  __shared__ float sth[4096];
  __shared__ float sxr[64][64];
  __shared__ float syt[64][65];
  int tid = threadIdx.x, w = tid>>6, lane = tid&63;
  int g = blockIdx.y;
  int r0 = blockIdx.x*64;
  const float* xg = x + (x_per_graph ? (size_t)g*N*64 : (size_t)0);
  for (int k = tid; k < 1024; k += 256) ((float4*)sth)[k] = ((const float4*)theta)[k];
  for (int rr = w; rr < 64; rr += 4){
    int r = r0 + rr;
    sxr[rr][lane] = (r < N) ? xg[(size_t)r*64 + lane] : 0.f;
  }
  __syncthreads();
  for (int rr = w*16; rr < w*16+16; rr++){
    float acc = 0.f;
    for (int d = 0; d < 64; d++) acc = fmaf(sxr[rr][d], sth[d*64 + lane], acc);
    syt[lane][rr] = acc;                 // bank (lane+rr)%32 -> conflict-free
  }
  __syncthreads();
  int col = r0 + lane;
  if (col < KP){
    for (int f = w*16; f < w*16+16; f++)
      xtT[((size_t)g*64 + f)*KP + col] = f2bf(syt[f][lane]);
  }
}

// MFMA conv GEMM. One wave = 16 rows x 16 cols (nt = blockIdx.x & 3):
// R9 ran 594 single-wave blocks (~2.3 waves/CU, latency-bound); N-split
// quadruples wave count. Adjacent blockIdx.x share the A row-tile (L2 reuse).
// mode 0: Yt[g][f][m] bf16 = acc*scale[m] (pads->0); mode 1: Yf[g][m][f] fp32 leaky(+bias)
__global__ __launch_bounds__(64) void k_gemm(const u16* __restrict__ A,
                                             const u16* __restrict__ Xt,
                                             int x_per_graph,
                                             const float* __restrict__ scale,
                                             const float* __restrict__ bias,
                                             int mode,
                                             u16* __restrict__ Yt,
                                             float* __restrict__ Yf){
  int g = blockIdx.y;
  int m0 = (blockIdx.x >> 2) * 16;
  int nt = blockIdx.x & 3;
  int lane = threadIdx.x;
  int mrow = lane & 15, quad = lane >> 4;
  const u16* Ap = A + (size_t)g*KP*KP + (size_t)(m0 + mrow)*KP + quad*8;
  const u16* Bp = Xt + (x_per_graph ? (size_t)g*64*KP : (size_t)0)
                     + (size_t)(nt*16 + mrow)*KP + quad*8;
  f32x4 acc = (f32x4){0.f,0.f,0.f,0.f};
  bf16x8 a0 = *(const bf16x8*)Ap;
  bf16x8 b0 = *(const bf16x8*)Bp;
  for (int c = 0; c < 33; c++){
    bf16x8 a1 = a0, b1 = b0;
    if (c < 32){
      a1 = *(const bf16x8*)(Ap + (c+1)*32);
      b1 = *(const bf16x8*)(Bp + (c+1)*32);
    }
    acc = __builtin_amdgcn_mfma_f32_16x16x32_bf16(a0, b0, acc, 0, 0, 0);
    a0 = a1; b0 = b1;
  }
  int mbase = m0 + quad*4;
  float sc_[4];
  #pragma unroll
  for (int r = 0; r < 4; r++){
    int m = mbase + r;
    sc_[r] = (m < N) ? scale[g*N + m] : 0.f;
  }
  if (mode == 0){
    ushort4 o;
    o.x = f2bf(acc[0]*sc_[0]);
    o.y = f2bf(acc[1]*sc_[1]);
    o.z = f2bf(acc[2]*sc_[2]);
    o.w = f2bf(acc[3]*sc_[3]);
    *(ushort4*)(Yt + ((size_t)g*64 + nt*16 + mrow)*KP + mbase) = o;
  } else {
    float bs = bias[nt*16 + mrow];
    #pragma unroll
    for (int r = 0; r < 4; r++){
      int m = mbase + r;
      if (m < N){
        float v = acc[r]*sc_[r] + bs;
        Yf[((size_t)g*N + m)*64 + nt*16 + mrow] = leakyf(v);
      }
    }
  }
}

// fused bmean + zred: 1024 threads + float4 (R9: 7 blocks x 256 thr, 0.3%
// occupancy, 257 serial scalar iters -> 125 us latency-bound)
__global__ __launch_bounds__(1024) void k_bz(const float* __restrict__ x2,
                                             const float* __restrict__ a_param,
                                             float* __restrict__ zout){
  int k = blockIdx.x, tid = threadIdx.x;
  int wv = tid >> 6, lane = tid & 63;
  const float4* a4 = (const float4*)(x2 + (size_t)k*NH);
  const float4* c4 = (const float4*)(x2 + (size_t)(k+1)*NH);
  __shared__ float red[16];
  __shared__ float sbk;
  float s = 0.f;
  #pragma unroll 4
  for (int i = tid; i < NH/4; i += 1024){
    float4 cc = c4[i], aa = a4[i];
    s += (cc.x-aa.x)+(cc.y-aa.y)+(cc.z-aa.z)+(cc.w-aa.w);
  }
  for (int off = 32; off; off >>= 1) s += __shfl_down(s, off);
  if (lane == 0) red[wv] = s;
  __syncthreads();
  if (tid == 0){
    float t = 0.f;
    for (int i = 0; i < 16; i++) t += red[i];
    sbk = t / (float)NH;
  }
  __syncthreads();
  float bk = sbk, ap = a_param[k];
  float s2 = 0.f;
  #pragma unroll 4
  for (int i = tid; i < NH/4; i += 1024){
    float4 cc = c4[i], aa = a4[i];
    float sb[4] = {cc.x-aa.x, cc.y-aa.y, cc.z-aa.z, cc.w-aa.w};
    #pragma unroll
    for (int j = 0; j < 4; j++){
      float U = 1.f/(1.f + ap*(bk - sb[j]));
      s2 += (U*sb[j])/U;
    }
  }
  for (int off = 32; off; off >>= 1) s2 += __shfl_down(s2, off);
  if (lane == 0) red[wv] = s2;
  __syncthreads();
  if (tid == 0){
    float t = 0.f;
    for (int i = 0; i < 16; i++) t += red[i];
    zout[k] = t;
  }
}

// final projection with inline wattn (softmax(w2 @ leaky(w1 @ z))) and dtype detect
__global__ __launch_bounds__(256) void k_final(const float* __restrict__ x2,
                                               const float* __restrict__ zv,
                                               const float* __restrict__ w1,
                                               const float* __restrict__ w2,
                                               const float* __restrict__ Wl,
                                               const float* __restrict__ bl,
                                               const u16* __restrict__ wihRaw,
                                               void* __restrict__ outv){
  __shared__ float sy[64];
  __shared__ float swa[8];
  int tid = threadIdx.x;
  int isf32 = detect_f32(wihRaw);
  if (tid < 64){
    float y = 0.f;
    for (int kk = 0; kk < TM; kk++) y += w1[tid*TM + kk]*zv[kk];
    sy[tid] = leakyf(y);
  }
  __syncthreads();
  if (tid < TM){
    float v = 0.f;
    for (int d = 0; d < 64; d++) v += w2[tid*64 + d]*sy[d];
    swa[tid] = v;
  }
  __syncthreads();
  if (tid == 0){
    float m = swa[0];
    for (int t = 1; t < TM; t++) m = fmaxf(m, swa[t]);
    float den = 0.f;
    for (int t = 0; t < TM; t++){ swa[t] = expf(swa[t]-m); den += swa[t]; }
    for (int t = 0; t < TM; t++) swa[t] /= den;
  }
  __syncthreads();
  int n = blockIdx.x*256 + tid;
  if (n < N){
    float w0 = swa[0], w2v = swa[2];
    float acc = bl[0];
    for (int h = 0; h < 64; h++){
      float xg = x2[(size_t)8*NH + (size_t)n*64 + h];
      float s0 = x2[(size_t)1*NH + (size_t)n*64 + h] - x2[(size_t)0*NH + (size_t)n*64 + h];
      float s2 = x2[(size_t)3*NH + (size_t)n*64 + h] - x2[(size_t)2*NH + (size_t)n*64 + h];
      float xx = w0*s0 + w2v*s2;
      acc += xg*Wl[h] + xx*Wl[64 + h];
    }
    float r = leakyf(acc);
    if (isf32) ((float*)outv)[n] = r;
    else       ((__hip_bfloat16*)outv)[n] = __float2bfloat16(r);
  }
}

extern "C" void kernel_launch(void* const* d_in, const int* in_sizes, int n_in,
                              void* d_out, int out_size, void* d_ws, size_t ws_size,
                              hipStream_t stream) {
  const int* hypT = (const int*)d_in[1];
  const int* hyp  = (const int*)d_in[2];

  char* p = (char*)d_ws;
  auto alloc = [&](size_t bytes) -> char* {
    char* r = p; p += (bytes + 63) & ~(size_t)63; return r;
  };
  float* cv   = (float*)alloc((size_t)TOT_CVT*4);
  u16* AHm    = (u16*)  alloc((size_t)NG*KP*KP*2);
  u16* AHmT   = (u16*)  alloc((size_t)NG*KP*KP*2);
  float* Dinv = (float*)alloc((size_t)NG*N*4);
  float* Binv = (float*)alloc((size_t)NG*N*4);
  float* ctx  = (float*)alloc((size_t)N*T*H*4);
  float* last = (float*)alloc((size_t)N*H*4);
  float* outp = (float*)alloc((size_t)N*H*4);
  float* x1   = (float*)alloc((size_t)NG*N*H*4);
  float* x2   = (float*)alloc((size_t)NG*N*H*4);
  float* zv   = (float*)alloc(64);
  u16* xtT1   = (u16*)  alloc((size_t)64*KP*2);
  u16* xtT2   = (u16*)  alloc((size_t)NG*64*KP*2);
  u16* ebufT  = (u16*)  alloc((size_t)NG*64*KP*2);

  const float* price  = cv + OFF_PRICE;
  const float* Wih    = cv + OFF_WIH;
  const float* Whh    = cv + OFF_WHH;
  const float* bih    = cv + OFF_BIH;
  const float* bhh    = cv + OFF_BHH;
  const float* Win    = cv + OFF_WIN;
  const float* Wout   = cv + OFF_WOUT;
  const float* ae     = cv + OFF_AE;
  const float* ab     = cv + OFF_AB;
  const float* theta1 = cv + OFF_TH1;
  const float* bias1  = cv + OFF_B1;
  const float* theta2 = cv + OFF_TH2;
  const float* bias2  = cv + OFF_B2;
  const float* w1     = cv + OFF_W1;
  const float* w2     = cv + OFF_W2;
  const float* a_par  = cv + OFF_APAR;
  const float* Wl     = cv + OFF_WL;
  const float* bl     = cv + OFF_BL;

  CvtPtrs ps;
  ps.p[0]=d_in[0];  ps.p[1]=d_in[3];  ps.p[2]=d_in[4];  ps.p[3]=d_in[5];
  ps.p[4]=d_in[6];  ps.p[5]=d_in[7];  ps.p[6]=d_in[8];  ps.p[7]=d_in[9];
  ps.p[8]=d_in[10]; ps.p[9]=d_in[11]; ps.p[10]=d_in[12]; ps.p[11]=d_in[13];
  ps.p[12]=d_in[14]; ps.p[13]=d_in[15]; ps.p[14]=d_in[16]; ps.p[15]=d_in[17];
  ps.p[16]=d_in[18]; ps.p[17]=d_in[19];
  k_cvt<<<(TOT_CVT+255)/256, 256, 0, stream>>>(ps, cv);

  k_build<<<dim3(NT, NG, 2), 1024, 0, stream>>>(hypT, hyp, AHm, AHmT, Dinv, Binv);
  k_gru  <<<(N+3)/4, 256, 0, stream>>>(price, Wih, Whh, bih, bhh, ctx, last);
  k_attn <<<(N+3)/4, 256, 0, stream>>>(ctx, last, Win, Wout, ae, ab, outp);

  // layer 1
  k_xthetaT<<<dim3(17, 1), 256, 0, stream>>>(outp, theta1, 0, xtT1);
  k_gemm<<<dim3((KP/16)*4, NG), 64, 0, stream>>>(AHmT, xtT1, 0, Binv, nullptr, 0, ebufT, nullptr);
  k_gemm<<<dim3((KP/16)*4, NG), 64, 0, stream>>>(AHm, ebufT, 1, Dinv, bias1, 1, nullptr, x1);

  // layer 2
  k_xthetaT<<<dim3(17, NG), 256, 0, stream>>>(x1, theta2, 1, xtT2);
  k_gemm<<<dim3((KP/16)*4, NG), 64, 0, stream>>>(AHmT, xtT2, 1, Binv, nullptr, 0, ebufT, nullptr);
  k_gemm<<<dim3((KP/16)*4, NG), 64, 0, stream>>>(AHm, ebufT, 1, Dinv, bias2, 1, nullptr, x2);

  k_bz<<<TM, 1024, 0, stream>>>(x2, a_par, zv);
  k_final<<<(N+255)/256, 256, 0, stream>>>(x2, zv, w1, w2, Wl, bl,
                                           (const u16*)d_in[3], d_out);
}